// Round 10
// baseline (5585.931 us; speedup 1.0000x reference)
//
#include <hip/hip_runtime.h>
#include <stdint.h>

typedef __attribute__((ext_vector_type(4))) float f32x4;
typedef __attribute__((ext_vector_type(8))) short bf16x8;
typedef __attribute__((ext_vector_type(4))) int i32x4;
typedef unsigned short ushort_t;
typedef unsigned long long u64;

#define S_LEN 512
#define BATCH 64
#define HSZ   1024
#define G4    4096
#define NWG   256
#define NTHR  256
// dynamic LDS: V slice 64KB | H tile 64KB | gbuf 32*33 floats
#define SMEM_BYTES (65536 + 65536 + 32 * 33 * 4)

// ---------- numeric helpers ----------

__device__ __forceinline__ float bf16r(float x) {
    union { float f; uint32_t u; } v; v.f = x;
    v.u = (v.u + 0x7FFFu + ((v.u >> 16) & 1u)) & 0xFFFF0000u;
    return v.f;
}

__device__ __forceinline__ ushort_t bf16bits(float x) {
    union { float f; uint32_t u; } v; v.f = x;
    uint32_t r = v.u + 0x7FFFu + ((v.u >> 16) & 1u);
    return (ushort_t)(r >> 16);
}

// BFP block of 8 (MAN=7): step = 2^(floor(log2(max|v|))-7); q = rint(v/step)*step.
// Every q is exactly representable in bf16 (<= 9 significant bits).
__device__ __forceinline__ void bfp8_quant(const float v[8], ushort_t o[8]) {
    float m = 0.f;
    #pragma unroll
    for (int i = 0; i < 8; ++i) m = fmaxf(m, fabsf(v[i]));
    if (m > 0.f) {
        int e;
        (void)frexpf(m, &e);
        float inv_step = ldexpf(1.0f, 8 - e);
        float step     = ldexpf(1.0f, e - 8);
        #pragma unroll
        for (int i = 0; i < 8; ++i) {
            float q = rintf(v[i] * inv_step) * step;  // exact pow2 scaling
            o[i] = bf16bits(q);                        // exact (<=9 sig bits)
        }
    } else {
        #pragma unroll
        for (int i = 0; i < 8; ++i) o[i] = 0;
    }
}

__device__ __forceinline__ void bfp8_store(const float* __restrict__ src,
                                           ushort_t* __restrict__ dst) {
    float v[8];
    float4 a = ((const float4*)src)[0];
    float4 b = ((const float4*)src)[1];
    v[0]=a.x; v[1]=a.y; v[2]=a.z; v[3]=a.w;
    v[4]=b.x; v[5]=b.y; v[6]=b.z; v[7]=b.w;
    union { ushort_t us[8]; int4 i4; } o;
    bfp8_quant(v, o.us);
    *(int4*)dst = o.i4;
}

// single-value quantize given the 8-block max
__device__ __forceinline__ ushort_t bfp_one(float v, float m) {
    if (!(m > 0.f)) return 0;
    int e;
    (void)frexpf(m, &e);
    float q = rintf(ldexpf(v, 8 - e)) * ldexpf(1.f, e - 8);
    return bf16bits(q);
}

// ---------- setup kernels ----------

// Pack quantized U and V per (gslice, cc): row n = q*1024 + gslice*8 + jj -> [gslice][cc=q*8+jj][k].
__global__ __launch_bounds__(256) void quant_weights_pack(
    const float* __restrict__ U, const float* __restrict__ V,
    ushort_t* __restrict__ Up, ushort_t* __restrict__ Vp,
    const float* __restrict__ bih, const float* __restrict__ bhh,
    float* __restrict__ bq)
{
    int blk = blockIdx.x * 256 + threadIdx.x;   // 0 .. 1048575
    int mtx = blk >> 19;
    int r = blk & 524287;
    int n = r >> 7, kb = r & 127;
    int q = n >> 10, j = n & 1023;
    int gslice = j >> 3, jj = j & 7;
    int cc = q * 8 + jj;
    const float* src = (mtx == 0 ? U : V) + (size_t)n * 1024 + kb * 8;
    ushort_t* dst = (mtx == 0 ? Up : Vp) + ((size_t)gslice * 32 + cc) * 1024 + kb * 8;
    bfp8_store(src, dst);
    if (blk < 4096) bq[blk] = bf16r(bih[blk]) + bf16r(bhh[blk]);
}

// hq0 = bfp(h0); c_ws = c0 raw.
__global__ __launch_bounds__(256) void init_state(
    const float* __restrict__ h0, const float* __restrict__ c0,
    ushort_t* __restrict__ hq0, float* __restrict__ c_ws)
{
    int idx = blockIdx.x * 256 + threadIdx.x;   // 0..8191
    int b = idx >> 7, j0 = (idx & 127) * 8;
    bfp8_store(h0 + (size_t)b * 1024 + j0, hq0 + (size_t)b * 1024 + j0);
    const float4* src = (const float4*)(c0 + (size_t)b * 1024 + j0);
    float4* dst = (float4*)(c_ws + (size_t)b * 1024 + j0);
    dst[0] = src[0]; dst[1] = src[1];
}

// Quantize ALL x steps: memory-bound pre-pass.
__global__ __launch_bounds__(256) void quant_x_all(
    const float* __restrict__ x, ushort_t* __restrict__ xq)
{
    int idx = blockIdx.x * 256 + threadIdx.x;   // 0 .. 4194303
    int r = idx >> 7, j0 = (idx & 127) * 8;     // r = t*64 + b
    bfp8_store(x + (size_t)r * 1024 + j0, xq + (size_t)r * 1024 + j0);
}

// ---------- MFMA passes (K=1024 -> 32 MFMAs) ----------

// h@V: both operands from XOR-swizzled LDS.
__device__ __forceinline__ f32x4 mm32_ll(const char* __restrict__ Alds, int arow,
                                         const char* __restrict__ Blds, int brow,
                                         int lg16, f32x4 acc) {
    const int aswz = (arow & 15) << 4;
    const int bswz = (brow & 15) << 4;
    const char* abase = Alds + arow * 2048;
    const char* bbase = Blds + brow * 2048;
    f32x4 acc2 = {0.f, 0.f, 0.f, 0.f};
    #pragma unroll
    for (int i = 0; i < 32; i += 2) {
        bf16x8 a0 = *(const bf16x8*)(abase + ((i * 64 + lg16) ^ aswz));
        bf16x8 b0 = *(const bf16x8*)(bbase + ((i * 64 + lg16) ^ bswz));
        bf16x8 a1 = *(const bf16x8*)(abase + (((i + 1) * 64 + lg16) ^ aswz));
        bf16x8 b1 = *(const bf16x8*)(bbase + (((i + 1) * 64 + lg16) ^ bswz));
        acc  = __builtin_amdgcn_mfma_f32_16x16x32_bf16(a0, b0, acc,  0, 0, 0);
        acc2 = __builtin_amdgcn_mfma_f32_16x16x32_bf16(a1, b1, acc2, 0, 0, 0);
    }
    return acc + acc2;
}

// x@U: both operands from global (L2-cacheable, clean data), chunked for VGPR.
// NOTE: both ap and bp must already include the lane-group k-offset (lg*8).
__device__ __forceinline__ f32x4 mm32_gg(const ushort_t* __restrict__ ap,
                                         const ushort_t* __restrict__ bp,
                                         f32x4 acc) {
    f32x4 acc2 = {0.f, 0.f, 0.f, 0.f};
    #pragma unroll
    for (int c = 0; c < 4; ++c) {
        bf16x8 a[8], b[8];
        #pragma unroll
        for (int i = 0; i < 8; ++i) {
            a[i] = *(const bf16x8*)(ap + (c * 8 + i) * 32);
            b[i] = *(const bf16x8*)(bp + (c * 8 + i) * 32);
        }
        #pragma unroll
        for (int i = 0; i < 8; ++i) {
            if (i & 1) acc2 = __builtin_amdgcn_mfma_f32_16x16x32_bf16(a[i], b[i], acc2, 0, 0, 0);
            else       acc  = __builtin_amdgcn_mfma_f32_16x16x32_bf16(a[i], b[i], acc,  0, 0, 0);
        }
    }
    return acc + acc2;
}

// Fallback: x@U with on-the-fly A quantization from f32 x, B from global.
__device__ __forceinline__ f32x4 mm32_xu_g(const float* __restrict__ xrow,
                                           const ushort_t* __restrict__ bp,
                                           f32x4 acc) {
    f32x4 acc2 = {0.f, 0.f, 0.f, 0.f};
    #pragma unroll
    for (int c = 0; c < 4; ++c) {
        float4 f[8][2];
        bf16x8 b[8];
        #pragma unroll
        for (int i = 0; i < 8; ++i) {
            f[i][0] = *(const float4*)(xrow + (c * 8 + i) * 32);
            f[i][1] = *(const float4*)(xrow + (c * 8 + i) * 32 + 4);
            b[i] = *(const bf16x8*)(bp + (c * 8 + i) * 32);
        }
        #pragma unroll
        for (int i = 0; i < 8; ++i) {
            float vv[8] = { f[i][0].x, f[i][0].y, f[i][0].z, f[i][0].w,
                            f[i][1].x, f[i][1].y, f[i][1].z, f[i][1].w };
            union { ushort_t us[8]; bf16x8 v; } aa;
            bfp8_quant(vv, aa.us);
            if (i & 1) acc2 = __builtin_amdgcn_mfma_f32_16x16x32_bf16(aa.v, b[i], acc2, 0, 0, 0);
            else       acc  = __builtin_amdgcn_mfma_f32_16x16x32_bf16(aa.v, b[i], acc,  0, 0, 0);
        }
    }
    return acc + acc2;
}

// ---------- persistent LSTM kernel: all 512 steps ----------

__global__ __launch_bounds__(256, 1) void lstm_persist(
    const float* __restrict__ x,        // [512][64][1024]
    const ushort_t* __restrict__ xq,    // [512][64][1024] bf16 (or null -> fallback)
    const ushort_t* __restrict__ Up,    // [128][32][1024]
    const ushort_t* __restrict__ Vp,    // [128][32][1024]
    const float* __restrict__ bq,       // [4096]
    const float* __restrict__ c0_ws,    // [64][1024]
    ushort_t* __restrict__ hq0, ushort_t* __restrict__ hq1,   // [64][1024] each
    float* __restrict__ out, float* __restrict__ hT, float* __restrict__ cT,
    unsigned int* __restrict__ barrier_cnt)   // [2][256] u32: 8 counters/half, 128B apart
{
    extern __shared__ char smem[];
    char* Vlds = smem;
    char* Hlds = smem + 65536;
    float* gbuf = (float*)(smem + 131072);

    const int tid = threadIdx.x;
    const int bx = blockIdx.x;
    const int gs = bx & 127;            // hidden-column slice (8 cols)
    const int ms = bx >> 7;             // batch half
    const int j0 = gs * 8;
    const int lane = tid & 63, wid = tid >> 6;
    const int wm = wid >> 1, wn = wid & 1;
    const int lr = lane & 15, lg = lane >> 4;
    const int lg16 = lg * 16;
    const int brow = wn * 16 + lr;      // packed gate-col cc in [0,32)
    const int arow_l = wm * 16 + lr;    // local A row within the half
    const int arow = ms * 32 + arow_l;  // global batch row for xq
    const bool use_xq = (xq != nullptr);

    // stage this wg's V slice into LDS (16-slot XOR swizzle)
    {
        const int4* vpg = (const int4*)(Vp + (size_t)gs * 32 * 1024);
        #pragma unroll
        for (int it = 0; it < 16; ++it) {
            int idx = tid + it * 256;
            int row = idx >> 7, kc = idx & 127;
            int off = row * 2048 + ((kc * 16) ^ ((row & 15) << 4));
            *(int4*)(Vlds + off) = vpg[idx];
        }
    }
    __syncthreads();

    const int q_gate = brow >> 3;
    const float bqv = bq[q_gate * 1024 + j0 + (brow & 7)];
    const f32x4 bq4 = {bqv, bqv, bqv, bqv};
    // this lane's U row, INCLUDING the lane-group k-offset (lg*8) — B-fragment
    // layout needs lane l to read k = kb*32 + (l>>4)*8 + [0..8).
    const ushort_t* Ub = Up + ((size_t)gs * 32 + brow) * 1024 + lg * 8;

    // epilogue mapping: thread owns (row urow of half, col j0+ujj); c in register
    const int urow = tid >> 3, ujj = tid & 7;
    const int bg = ms * 32 + urow;
    float c_reg = c0_ws[(size_t)bg * 1024 + j0 + ujj];

    // 8 barrier counters per half, 128B apart
    unsigned int* cnt = barrier_cnt + ms * 256;
    unsigned int* myc = cnt + (bx & 7) * 32;

    // x@U for t=0 (serial once)
    f32x4 xUacc = use_xq
        ? mm32_gg(xq + (size_t)arow * 1024 + lg * 8, Ub, bq4)
        : mm32_xu_g(x + (size_t)arow * 1024 + lg * 8, Ub, bq4);

    for (int t = 0; t < S_LEN; ++t) {
        const bool doX = (t < S_LEN - 1);
        const ushort_t* hin = (t & 1) ? hq1 : hq0;
        ushort_t* hout = ((t + 1) & 1) ? hq1 : hq0;

        // ---- cooperative sc1 staging of the half's h tile (64KB) into LDS ----
        {
            const ushort_t* hsrc = hin + (size_t)ms * 32 * 1024;
            i32x4 hb[16];
            #pragma unroll
            for (int i = 0; i < 16; ++i) {
                asm volatile("global_load_dwordx4 %0, %1, off sc1"
                             : "=v"(hb[i])
                             : "v"(hsrc + ((size_t)(tid + i * 256)) * 8));   // 16B chunks
            }
            asm volatile("s_waitcnt vmcnt(0)" ::: "memory");
            __builtin_amdgcn_sched_barrier(0);
            #pragma unroll
            for (int i = 0; i < 16; ++i) {
                int c = tid + i * 256;
                int r = c >> 7, kb = (c & 127) * 16;
                *(i32x4*)(Hlds + r * 2048 + (kb ^ ((r & 15) << 4))) = hb[i];
            }
        }
        __syncthreads();

        // gates = b + x@U (carried) + h@V (pure LDS/LDS)
        f32x4 accG = mm32_ll(Hlds, arow_l, Vlds, brow, lg16, xUacc);

        // activations -> gbuf [32 rows][33 stride], col = cc
        #pragma unroll
        for (int r = 0; r < 4; ++r) {
            float gate = bf16r(accG[r]);
            float sig = 1.f / (1.f + expf(-gate));
            float th  = tanhf(gate);
            float act = bf16r(q_gate == 2 ? th : sig);
            gbuf[(wm * 16 + lg * 4 + r) * 33 + brow] = act;
        }
        __syncthreads();

        // c/h update: all 256 threads, one element each
        float i_t = gbuf[urow * 33 + ujj];
        float f_t = gbuf[urow * 33 + 8 + ujj];
        float g_t = gbuf[urow * 33 + 16 + ujj];
        float o_t = gbuf[urow * 33 + 24 + ujj];
        float cn = bf16r(__fadd_rn(__fmul_rn(f_t, c_reg), __fmul_rn(i_t, g_t)));
        float hn = bf16r(__fmul_rn(o_t, tanhf(cn)));
        c_reg = cn;

        // publish re-quantized h for next step (device-coherent sc1 stores)
        {
            float m = fabsf(hn);
            m = fmaxf(m, __shfl_xor(m, 1));
            m = fmaxf(m, __shfl_xor(m, 2));
            m = fmaxf(m, __shfl_xor(m, 4));
            uint32_t hv = (uint32_t)bfp_one(hn, m);
            uint32_t p1 = __shfl_xor(hv, 1);
            uint32_t w32 = hv | (p1 << 16);              // valid on even ujj
            uint32_t p2 = __shfl_xor(w32, 2);
            u64 w64 = ((u64)p2 << 32) | (u64)w32;        // valid on ujj==0,4
            if ((ujj & 3) == 0) {
                u64* dst = (u64*)(hout + (size_t)bg * 1024 + j0) + (ujj >> 2);
                __hip_atomic_store(dst, w64, __ATOMIC_RELAXED, __HIP_MEMORY_SCOPE_AGENT);
            }
        }

        if (doX) {
            // arrive: syncthreads drains vmcnt (h sc1-stores ack'd) before the add
            __syncthreads();
            if (tid == 0)
                __hip_atomic_fetch_add(myc, 1u, __ATOMIC_RELAXED, __HIP_MEMORY_SCOPE_AGENT);
        }

        // out / final-state stores: not consumed cross-wg, off the arrive path
        __builtin_nontemporal_store(hn, out + (size_t)t * (BATCH * HSZ) + (size_t)bg * 1024 + j0 + ujj);
        if (t == S_LEN - 1) {
            __builtin_nontemporal_store(hn, hT + (size_t)bg * 1024 + j0 + ujj);
            __builtin_nontemporal_store(cn, cT + (size_t)bg * 1024 + j0 + ujj);
        }

        if (doX) {
            // overlap: x@U for step t+1 inside the barrier window (L2-served)
            f32x4 accX = use_xq
                ? mm32_gg(xq + (size_t)(t + 1) * (BATCH * HSZ) + (size_t)arow * 1024 + lg * 8, Ub, bq4)
                : mm32_xu_g(x + (size_t)(t + 1) * (BATCH * HSZ) + (size_t)arow * 1024 + lg * 8, Ub, bq4);

            // wait: sum of the 8 counters >= 128*(t+1).
            if (wid == 0) {
                const unsigned tgt = 128u * (unsigned)(t + 1);
                while (true) {
                    unsigned v = (lane < 8)
                        ? __hip_atomic_load(cnt + lane * 32, __ATOMIC_RELAXED, __HIP_MEMORY_SCOPE_AGENT)
                        : 0u;
                    #pragma unroll
                    for (int s = 1; s < 64; s <<= 1)
                        v += (unsigned)__shfl_xor((int)v, s);
                    if (v >= tgt) break;
                    __builtin_amdgcn_s_sleep(1);
                }
            }
            __syncthreads();
            xUacc = accX;
        }
    }
}

// ---------- launcher ----------

extern "C" void kernel_launch(void* const* d_in, const int* in_sizes, int n_in,
                              void* d_out, int out_size, void* d_ws, size_t ws_size,
                              hipStream_t stream) {
    const float* x   = (const float*)d_in[0];
    const float* h0  = (const float*)d_in[1];
    const float* c0  = (const float*)d_in[2];
    const float* U   = (const float*)d_in[3];
    const float* V   = (const float*)d_in[4];
    const float* bih = (const float*)d_in[5];
    const float* bhh = (const float*)d_in[6];

    float* out = (float*)d_out;
    float* hT  = out + (size_t)S_LEN * BATCH * HSZ;
    float* cT  = hT + (size_t)BATCH * HSZ;

    char* p = (char*)d_ws;
    ushort_t* Up  = (ushort_t*)p; p += (size_t)G4 * 1024 * 2;      // 8 MB
    ushort_t* Vp  = (ushort_t*)p; p += (size_t)G4 * 1024 * 2;      // 8 MB
    float* bq     = (float*)p;    p += (size_t)G4 * 4;             // 16 KB
    float* c_ws   = (float*)p;    p += (size_t)BATCH * HSZ * 4;    // 256 KB
    ushort_t* hq0 = (ushort_t*)p; p += (size_t)BATCH * HSZ * 2;    // 128 KB
    ushort_t* hq1 = (ushort_t*)p; p += (size_t)BATCH * HSZ * 2;
    unsigned int* cnt = (unsigned int*)p; p += 2048;               // 2 halves x 256 u32
    // align to 256B
    p = (char*)(((uintptr_t)p + 255) & ~(uintptr_t)255);
    size_t xq_bytes = (size_t)S_LEN * BATCH * HSZ * 2;             // 64 MB
    ushort_t* xq = nullptr;
    if ((size_t)(p - (char*)d_ws) + xq_bytes <= ws_size)
        xq = (ushort_t*)p;

    hipMemsetAsync(cnt, 0, 2048, stream);
    hipLaunchKernelGGL(quant_weights_pack, dim3(4096), dim3(256), 0, stream,
                       U, V, Up, Vp, bih, bhh, bq);
    hipLaunchKernelGGL(init_state, dim3(32), dim3(256), 0, stream, h0, c0, hq0, c_ws);
    if (xq)
        hipLaunchKernelGGL(quant_x_all, dim3(16384), dim3(256), 0, stream, x, xq);

    hipFuncSetAttribute(reinterpret_cast<const void*>(lstm_persist),
                        hipFuncAttributeMaxDynamicSharedMemorySize, SMEM_BYTES);

    void* args[] = {
        (void*)&x, (void*)&xq, (void*)&Up, (void*)&Vp, (void*)&bq, (void*)&c_ws,
        (void*)&hq0, (void*)&hq1,
        (void*)&out, (void*)&hT, (void*)&cT, (void*)&cnt
    };
    hipLaunchCooperativeKernel(reinterpret_cast<void*>(lstm_persist),
                               dim3(NWG), dim3(NTHR), args, SMEM_BYTES, stream);
}

// Round 14
// 5135.126 us; speedup vs baseline: 1.0878x; 1.0878x over previous
//
#include <hip/hip_runtime.h>
#include <stdint.h>

typedef __attribute__((ext_vector_type(4))) float f32x4;
typedef __attribute__((ext_vector_type(8))) short bf16x8;
typedef __attribute__((ext_vector_type(4))) int i32x4;
typedef unsigned short ushort_t;
typedef unsigned long long u64;

#define S_LEN 512
#define BATCH 64
#define HSZ   1024
#define G4    4096
#define NWG   256
#define NTHR  256
// dynamic LDS: V slice 64KB | U slice 64KB | gbuf 32*33 floats
#define SMEM_BYTES (65536 + 65536 + 32 * 33 * 4)

// ---------- numeric helpers ----------

__device__ __forceinline__ float bf16r(float x) {
    union { float f; uint32_t u; } v; v.f = x;
    v.u = (v.u + 0x7FFFu + ((v.u >> 16) & 1u)) & 0xFFFF0000u;
    return v.f;
}

__device__ __forceinline__ ushort_t bf16bits(float x) {
    union { float f; uint32_t u; } v; v.f = x;
    uint32_t r = v.u + 0x7FFFu + ((v.u >> 16) & 1u);
    return (ushort_t)(r >> 16);
}

// BFP block of 8 (MAN=7): step = 2^(floor(log2(max|v|))-7); q = rint(v/step)*step.
// Every q is exactly representable in bf16 (<= 9 significant bits).
__device__ __forceinline__ void bfp8_quant(const float v[8], ushort_t o[8]) {
    float m = 0.f;
    #pragma unroll
    for (int i = 0; i < 8; ++i) m = fmaxf(m, fabsf(v[i]));
    if (m > 0.f) {
        int e;
        (void)frexpf(m, &e);
        float inv_step = ldexpf(1.0f, 8 - e);
        float step     = ldexpf(1.0f, e - 8);
        #pragma unroll
        for (int i = 0; i < 8; ++i) {
            float q = rintf(v[i] * inv_step) * step;  // exact pow2 scaling
            o[i] = bf16bits(q);                        // exact (<=9 sig bits)
        }
    } else {
        #pragma unroll
        for (int i = 0; i < 8; ++i) o[i] = 0;
    }
}

__device__ __forceinline__ void bfp8_store(const float* __restrict__ src,
                                           ushort_t* __restrict__ dst) {
    float v[8];
    float4 a = ((const float4*)src)[0];
    float4 b = ((const float4*)src)[1];
    v[0]=a.x; v[1]=a.y; v[2]=a.z; v[3]=a.w;
    v[4]=b.x; v[5]=b.y; v[6]=b.z; v[7]=b.w;
    union { ushort_t us[8]; int4 i4; } o;
    bfp8_quant(v, o.us);
    *(int4*)dst = o.i4;
}

// single-value quantize given the 8-block max
__device__ __forceinline__ ushort_t bfp_one(float v, float m) {
    if (!(m > 0.f)) return 0;
    int e;
    (void)frexpf(m, &e);
    float q = rintf(ldexpf(v, 8 - e)) * ldexpf(1.f, e - 8);
    return bf16bits(q);
}

// ---------- setup kernels ----------

// Pack quantized U and V per (gslice, cc): row n = q*1024 + gslice*8 + jj -> [gslice][cc=q*8+jj][k].
__global__ __launch_bounds__(256) void quant_weights_pack(
    const float* __restrict__ U, const float* __restrict__ V,
    ushort_t* __restrict__ Up, ushort_t* __restrict__ Vp,
    const float* __restrict__ bih, const float* __restrict__ bhh,
    float* __restrict__ bq)
{
    int blk = blockIdx.x * 256 + threadIdx.x;   // 0 .. 1048575
    int mtx = blk >> 19;
    int r = blk & 524287;
    int n = r >> 7, kb = r & 127;
    int q = n >> 10, j = n & 1023;
    int gslice = j >> 3, jj = j & 7;
    int cc = q * 8 + jj;
    const float* src = (mtx == 0 ? U : V) + (size_t)n * 1024 + kb * 8;
    ushort_t* dst = (mtx == 0 ? Up : Vp) + ((size_t)gslice * 32 + cc) * 1024 + kb * 8;
    bfp8_store(src, dst);
    if (blk < 4096) bq[blk] = bf16r(bih[blk]) + bf16r(bhh[blk]);
}

// hq0 = bfp(h0); c_ws = c0 raw.
__global__ __launch_bounds__(256) void init_state(
    const float* __restrict__ h0, const float* __restrict__ c0,
    ushort_t* __restrict__ hq0, float* __restrict__ c_ws)
{
    int idx = blockIdx.x * 256 + threadIdx.x;   // 0..8191
    int b = idx >> 7, j0 = (idx & 127) * 8;
    bfp8_store(h0 + (size_t)b * 1024 + j0, hq0 + (size_t)b * 1024 + j0);
    const float4* src = (const float4*)(c0 + (size_t)b * 1024 + j0);
    float4* dst = (float4*)(c_ws + (size_t)b * 1024 + j0);
    dst[0] = src[0]; dst[1] = src[1];
}

// Quantize ALL x steps: memory-bound pre-pass.
__global__ __launch_bounds__(256) void quant_x_all(
    const float* __restrict__ x, ushort_t* __restrict__ xq)
{
    int idx = blockIdx.x * 256 + threadIdx.x;   // 0 .. 4194303
    int r = idx >> 7, j0 = (idx & 127) * 8;     // r = t*64 + b
    bfp8_store(x + (size_t)r * 1024 + j0, xq + (size_t)r * 1024 + j0);
}

// ---------- MFMA passes (K=1024 -> 32 MFMAs, B from swizzled LDS) ----------

__device__ __forceinline__ f32x4 mm32_frag(const bf16x8 a[32],
                                           const char* __restrict__ bbase,
                                           int bswz, int lg16, f32x4 acc) {
    f32x4 acc2 = {0.f, 0.f, 0.f, 0.f};
    #pragma unroll
    for (int i = 0; i < 32; i += 2) {
        bf16x8 b0 = *(const bf16x8*)(bbase + ((i * 64 + lg16) ^ bswz));
        bf16x8 b1 = *(const bf16x8*)(bbase + (((i + 1) * 64 + lg16) ^ bswz));
        acc  = __builtin_amdgcn_mfma_f32_16x16x32_bf16(a[i],     b0, acc,  0, 0, 0);
        acc2 = __builtin_amdgcn_mfma_f32_16x16x32_bf16(a[i + 1], b1, acc2, 0, 0, 0);
    }
    return acc + acc2;
}

// h@V: A-fragments via device-coherent 16B sc1 loads, issued as one pipelined
// batch (32 outstanding), then a single vmcnt(0) drain. Avoids the compiler's
// per-pair load->waitcnt->MFMA chaining (one LLC round trip per pair).
__device__ __forceinline__ f32x4 mm32_hv(const ushort_t* __restrict__ hrow,
                                         const char* __restrict__ Blds,
                                         int brow, int lg16, f32x4 acc) {
    union { i32x4 i; bf16x8 v; } a[32];
    #pragma unroll
    for (int i = 0; i < 32; ++i) {
        asm volatile("global_load_dwordx4 %0, %1, off sc1"
                     : "=v"(a[i].i)
                     : "v"(hrow + i * 32));   // byte offset i*64, 16B aligned
    }
    asm volatile("s_waitcnt vmcnt(0)" ::: "memory");
    __builtin_amdgcn_sched_barrier(0);
    bf16x8 af[32];
    #pragma unroll
    for (int i = 0; i < 32; ++i) af[i] = a[i].v;
    return mm32_frag(af, Blds + brow * 2048, (brow & 15) << 4, lg16, acc);
}

// x@U from pre-quantized xq: plain cached 16B loads.
__device__ __forceinline__ f32x4 mm32_xq(const ushort_t* __restrict__ xrow,
                                         const char* __restrict__ Blds,
                                         int brow, int lg16, f32x4 acc) {
    bf16x8 a[32];
    #pragma unroll
    for (int i = 0; i < 32; ++i)
        a[i] = *(const bf16x8*)(xrow + i * 32);
    return mm32_frag(a, Blds + brow * 2048, (brow & 15) << 4, lg16, acc);
}

// Fallback: x@U with on-the-fly quantization from f32 x (if ws can't hold xq).
__device__ __forceinline__ f32x4 mm32_xu(const float* __restrict__ xrow,
                                         const char* __restrict__ Blds,
                                         int brow, int lg16, f32x4 acc) {
    const int bswz = (brow & 15) << 4;
    const char* bbase = Blds + brow * 2048;
    f32x4 acc2 = {0.f, 0.f, 0.f, 0.f};
    #pragma unroll
    for (int c = 0; c < 4; ++c) {
        float4 f[8][2];
        #pragma unroll
        for (int i = 0; i < 8; ++i) {
            f[i][0] = *(const float4*)(xrow + (c * 8 + i) * 32);
            f[i][1] = *(const float4*)(xrow + (c * 8 + i) * 32 + 4);
        }
        #pragma unroll
        for (int i = 0; i < 8; ++i) {
            float vv[8] = { f[i][0].x, f[i][0].y, f[i][0].z, f[i][0].w,
                            f[i][1].x, f[i][1].y, f[i][1].z, f[i][1].w };
            union { ushort_t us[8]; bf16x8 v; } aa;
            bfp8_quant(vv, aa.us);
            int kb = c * 8 + i;
            bf16x8 b = *(const bf16x8*)(bbase + ((kb * 64 + lg16) ^ bswz));
            if (kb & 1) acc2 = __builtin_amdgcn_mfma_f32_16x16x32_bf16(aa.v, b, acc2, 0, 0, 0);
            else        acc  = __builtin_amdgcn_mfma_f32_16x16x32_bf16(aa.v, b, acc,  0, 0, 0);
        }
    }
    return acc + acc2;
}

// ---------- persistent LSTM kernel: all 512 steps ----------

__global__ __launch_bounds__(256, 1) void lstm_persist(
    const float* __restrict__ x,        // [512][64][1024]
    const ushort_t* __restrict__ xq,    // [512][64][1024] bf16 (or null -> fallback)
    const ushort_t* __restrict__ Up,    // [128][32][1024]
    const ushort_t* __restrict__ Vp,    // [128][32][1024]
    const float* __restrict__ bq,       // [4096]
    const float* __restrict__ c0_ws,    // [64][1024]
    ushort_t* __restrict__ hq0, ushort_t* __restrict__ hq1,   // [64][1024] each
    float* __restrict__ out, float* __restrict__ hT, float* __restrict__ cT,
    unsigned int* __restrict__ barrier_cnt)   // [2][256] u32: 8 counters/half, 128B apart
{
    extern __shared__ char smem[];
    char* Vlds = smem;
    char* Ulds = smem + 65536;
    float* gbuf = (float*)(smem + 131072);

    const int tid = threadIdx.x;
    const int bx = blockIdx.x;
    const int gs = bx & 127;            // hidden-column slice (8 cols)
    const int ms = bx >> 7;             // batch half
    const int j0 = gs * 8;
    const int lane = tid & 63, wid = tid >> 6;
    const int wm = wid >> 1, wn = wid & 1;
    const int lr = lane & 15, lg = lane >> 4;
    const int lg16 = lg * 16;
    const int brow = wn * 16 + lr;      // packed gate-col cc in [0,32)
    const int arow = ms * 32 + wm * 16 + lr;
    const bool use_xq = (xq != nullptr);

    // stage this wg's U/V slices into LDS (16-slot XOR swizzle)
    {
        const int4* upg = (const int4*)(Up + (size_t)gs * 32 * 1024);
        const int4* vpg = (const int4*)(Vp + (size_t)gs * 32 * 1024);
        for (int idx = tid; idx < 4096; idx += NTHR) {
            int row = idx >> 7, kc = idx & 127;
            int off = row * 2048 + ((kc * 16) ^ ((row & 15) << 4));
            *(int4*)(Ulds + off) = upg[idx];
            *(int4*)(Vlds + off) = vpg[idx];
        }
    }
    __syncthreads();

    const int q_gate = brow >> 3;
    const float bqv = bq[q_gate * 1024 + j0 + (brow & 7)];
    const f32x4 bq4 = {bqv, bqv, bqv, bqv};

    // epilogue mapping: thread owns (row urow of half, col j0+ujj); c in register
    const int urow = tid >> 3, ujj = tid & 7;
    const int bg = ms * 32 + urow;
    float c_reg = c0_ws[(size_t)bg * 1024 + j0 + ujj];

    // 8 barrier counters per half, 128B apart
    unsigned int* cnt = barrier_cnt + ms * 256;
    unsigned int* myc = cnt + (bx & 7) * 32;

    // x@U for t=0 (serial once)
    f32x4 xUacc = use_xq
        ? mm32_xq(xq + (size_t)arow * 1024 + lg * 8, Ulds, brow, lg16, bq4)
        : mm32_xu(x  + (size_t)arow * 1024 + lg * 8, Ulds, brow, lg16, bq4);

    for (int t = 0; t < S_LEN; ++t) {
        const bool doX = (t < S_LEN - 1);
        const ushort_t* hin = (t & 1) ? hq1 : hq0;
        ushort_t* hout = ((t + 1) & 1) ? hq1 : hq0;

        // gates = b + x@U (carried) + h@V
        f32x4 accG = mm32_hv(hin + (size_t)arow * 1024 + lg * 8, Vlds, brow, lg16, xUacc);

        // activations -> gbuf [32 rows][33 stride], col = cc
        #pragma unroll
        for (int r = 0; r < 4; ++r) {
            float gate = bf16r(accG[r]);
            float sig = 1.f / (1.f + expf(-gate));
            float th  = tanhf(gate);
            float act = bf16r(q_gate == 2 ? th : sig);
            gbuf[(wm * 16 + lg * 4 + r) * 33 + brow] = act;
        }
        __syncthreads();

        // c/h update: all 256 threads, one element each
        float i_t = gbuf[urow * 33 + ujj];
        float f_t = gbuf[urow * 33 + 8 + ujj];
        float g_t = gbuf[urow * 33 + 16 + ujj];
        float o_t = gbuf[urow * 33 + 24 + ujj];
        float cn = bf16r(__fadd_rn(__fmul_rn(f_t, c_reg), __fmul_rn(i_t, g_t)));
        float hn = bf16r(__fmul_rn(o_t, tanhf(cn)));
        c_reg = cn;

        // publish re-quantized h for next step (device-coherent sc1 stores)
        {
            float m = fabsf(hn);
            m = fmaxf(m, __shfl_xor(m, 1));
            m = fmaxf(m, __shfl_xor(m, 2));
            m = fmaxf(m, __shfl_xor(m, 4));
            uint32_t hv = (uint32_t)bfp_one(hn, m);
            uint32_t p1 = __shfl_xor(hv, 1);
            uint32_t w32 = hv | (p1 << 16);              // valid on even ujj
            uint32_t p2 = __shfl_xor(w32, 2);
            u64 w64 = ((u64)p2 << 32) | (u64)w32;        // valid on ujj==0,4
            if ((ujj & 3) == 0) {
                u64* dst = (u64*)(hout + (size_t)bg * 1024 + j0) + (ujj >> 2);
                __hip_atomic_store(dst, w64, __ATOMIC_RELAXED, __HIP_MEMORY_SCOPE_AGENT);
            }
        }

        if (doX) {
            // arrive: syncthreads drains vmcnt (h sc1-stores ack'd) before the add
            __syncthreads();
            if (tid == 0)
                __hip_atomic_fetch_add(myc, 1u, __ATOMIC_RELAXED, __HIP_MEMORY_SCOPE_AGENT);
        }

        // out / final-state stores: not consumed cross-wg, moved off the arrive path
        __builtin_nontemporal_store(hn, out + (size_t)t * (BATCH * HSZ) + (size_t)bg * 1024 + j0 + ujj);
        if (t == S_LEN - 1) {
            __builtin_nontemporal_store(hn, hT + (size_t)bg * 1024 + j0 + ujj);
            __builtin_nontemporal_store(cn, cT + (size_t)bg * 1024 + j0 + ujj);
        }

        if (doX) {
            // overlap: x@U for step t+1 inside the barrier window
            f32x4 accX = use_xq
                ? mm32_xq(xq + (size_t)(t + 1) * (BATCH * HSZ) + (size_t)arow * 1024 + lg * 8,
                          Ulds, brow, lg16, bq4)
                : mm32_xu(x  + (size_t)(t + 1) * (BATCH * HSZ) + (size_t)arow * 1024 + lg * 8,
                          Ulds, brow, lg16, bq4);

            // wait: sum of the 8 counters >= 128*(t+1).
            // wave 0: lanes 0-7 load the counters in one parallel round trip, shfl-sum.
            if (wid == 0) {
                const unsigned tgt = 128u * (unsigned)(t + 1);
                while (true) {
                    unsigned v = (lane < 8)
                        ? __hip_atomic_load(cnt + lane * 32, __ATOMIC_RELAXED, __HIP_MEMORY_SCOPE_AGENT)
                        : 0u;
                    #pragma unroll
                    for (int s = 1; s < 64; s <<= 1)
                        v += (unsigned)__shfl_xor((int)v, s);
                    if (v >= tgt) break;
                    __builtin_amdgcn_s_sleep(1);
                }
            }
            __syncthreads();
            xUacc = accX;
        }
    }
}

// ---------- launcher ----------

extern "C" void kernel_launch(void* const* d_in, const int* in_sizes, int n_in,
                              void* d_out, int out_size, void* d_ws, size_t ws_size,
                              hipStream_t stream) {
    const float* x   = (const float*)d_in[0];
    const float* h0  = (const float*)d_in[1];
    const float* c0  = (const float*)d_in[2];
    const float* U   = (const float*)d_in[3];
    const float* V   = (const float*)d_in[4];
    const float* bih = (const float*)d_in[5];
    const float* bhh = (const float*)d_in[6];

    float* out = (float*)d_out;
    float* hT  = out + (size_t)S_LEN * BATCH * HSZ;
    float* cT  = hT + (size_t)BATCH * HSZ;

    char* p = (char*)d_ws;
    ushort_t* Up  = (ushort_t*)p; p += (size_t)G4 * 1024 * 2;      // 8 MB
    ushort_t* Vp  = (ushort_t*)p; p += (size_t)G4 * 1024 * 2;      // 8 MB
    float* bq     = (float*)p;    p += (size_t)G4 * 4;             // 16 KB
    float* c_ws   = (float*)p;    p += (size_t)BATCH * HSZ * 4;    // 256 KB
    ushort_t* hq0 = (ushort_t*)p; p += (size_t)BATCH * HSZ * 2;    // 128 KB
    ushort_t* hq1 = (ushort_t*)p; p += (size_t)BATCH * HSZ * 2;
    unsigned int* cnt = (unsigned int*)p; p += 2048;               // 2 halves x 256 u32
    // align to 256B
    p = (char*)(((uintptr_t)p + 255) & ~(uintptr_t)255);
    size_t xq_bytes = (size_t)S_LEN * BATCH * HSZ * 2;             // 64 MB
    ushort_t* xq = nullptr;
    if ((size_t)(p - (char*)d_ws) + xq_bytes <= ws_size)
        xq = (ushort_t*)p;

    hipMemsetAsync(cnt, 0, 2048, stream);
    hipLaunchKernelGGL(quant_weights_pack, dim3(4096), dim3(256), 0, stream,
                       U, V, Up, Vp, bih, bhh, bq);
    hipLaunchKernelGGL(init_state, dim3(32), dim3(256), 0, stream, h0, c0, hq0, c_ws);
    if (xq)
        hipLaunchKernelGGL(quant_x_all, dim3(16384), dim3(256), 0, stream, x, xq);

    hipFuncSetAttribute(reinterpret_cast<const void*>(lstm_persist),
                        hipFuncAttributeMaxDynamicSharedMemorySize, SMEM_BYTES);

    void* args[] = {
        (void*)&x, (void*)&xq, (void*)&Up, (void*)&Vp, (void*)&bq, (void*)&c_ws,
        (void*)&hq0, (void*)&hq1,
        (void*)&out, (void*)&hT, (void*)&cT, (void*)&cnt
    };
    hipLaunchCooperativeKernel(reinterpret_cast<void*>(lstm_persist),
                               dim3(NWG), dim3(NTHR), args, SMEM_BYTES, stream);
}